// Round 1
// baseline (368.922 us; speedup 1.0000x reference)
//
#include <hip/hip_runtime.h>
#include <hip/hip_bf16.h>
#include <math.h>

#define B_N 512
#define C_N 100000
#define D_N 128
#define NCHUNK 1563  // ceil(100000/64)

typedef short short8 __attribute__((ext_vector_type(8)));
typedef float f32x4 __attribute__((ext_vector_type(4)));
typedef unsigned short u16x4 __attribute__((ext_vector_type(4)));

__device__ __forceinline__ unsigned short f2bf(float f) {
  // round-to-nearest-even fp32 -> bf16 (finite inputs)
  unsigned int u = __float_as_uint(f);
  u += 0x7fffu + ((u >> 16) & 1u);
  return (unsigned short)(u >> 16);
}

template <int NT>
__device__ __forceinline__ float block_reduce_sum(float v, float* red) {
  int t = threadIdx.x;
  __syncthreads();
  red[t] = v;
  __syncthreads();
#pragma unroll
  for (int s = NT / 2; s > 0; s >>= 1) {
    if (t < s) red[t] += red[t + s];
    __syncthreads();
  }
  return red[0];
}

// K1: Xn = l2norm(X)   grid 512, block 128
__global__ void k1_norm_x(const float* __restrict__ X, float* __restrict__ Xn) {
  __shared__ float red[128];
  int b = blockIdx.x, t = threadIdx.x;
  float v = X[b * D_N + t];
  float ss = block_reduce_sum<128>(v * v, red);
  Xn[b * D_N + t] = v / fmaxf(sqrtf(ss), 1e-12f);
}

// K2: Pb = l2norm(proxies[T[b]]); diag[b] = Pb[b].Xn[b]   grid 512, block 128
__global__ void k2_pb(const float* __restrict__ proxies, const int* __restrict__ T,
                      const float* __restrict__ Xn, float* __restrict__ Pb,
                      float* __restrict__ diagv) {
  __shared__ float red[128];
  int b = blockIdx.x, t = threadIdx.x;
  int row = T[b];
  float p = proxies[(size_t)row * D_N + t];
  float ss = block_reduce_sum<128>(p * p, red);
  float pn = p / fmaxf(sqrtf(ss), 1e-12f);
  Pb[b * D_N + t] = pn;
  float d = block_reduce_sum<128>(pn * Xn[b * D_N + t], red);
  if (t == 0) diagv[b] = d;
}

// K3: A[b,k] = relu(0.5*(Pb[b].Xn[k] + diag[k])) + relu(Xn[b].Xn[k]); S[b]=sum_k A[b,k]
// grid 512 (b), block 256
__global__ __launch_bounds__(256) void k3_att(const float* __restrict__ Xn,
                                              const float* __restrict__ Pb,
                                              const float* __restrict__ diagv,
                                              float* __restrict__ A, float* __restrict__ S) {
  __shared__ float xb[128], pbv[128];
  __shared__ float red[256];
  int b = blockIdx.x, t = threadIdx.x;
  if (t < 128) {
    xb[t] = Xn[b * D_N + t];
    pbv[t] = Pb[b * D_N + t];
  }
  __syncthreads();
  float rs = 0.f;
  for (int k = t; k < B_N; k += 256) {
    const float4* xr = (const float4*)(Xn + (size_t)k * D_N);
    float d1 = 0.f, d2 = 0.f;
#pragma unroll
    for (int i = 0; i < 32; i++) {
      float4 v = xr[i];
      d1 += pbv[4 * i] * v.x + pbv[4 * i + 1] * v.y + pbv[4 * i + 2] * v.z + pbv[4 * i + 3] * v.w;
      d2 += xb[4 * i] * v.x + xb[4 * i + 1] * v.y + xb[4 * i + 2] * v.z + xb[4 * i + 3] * v.w;
    }
    float a = fmaxf(0.5f * (d1 + diagv[k]), 0.f) + fmaxf(d2, 0.f);
    A[(size_t)b * B_N + k] = a;
    rs += a;
  }
  rs = block_reduce_sum<256>(rs, red);
  if (t == 0) S[b] = rs;
}

// K4: AW = (A/colS) @ Xn ; X2 = Xn + AW ; Xs = 3*l2norm(X2) ; lossT[b] = Dm[b,T[b]]
// grid 512 (b), block 128 (d)
__global__ void k4_xs(const float* __restrict__ Xn, const float* __restrict__ Pb,
                      const float* __restrict__ A, const float* __restrict__ S,
                      float* __restrict__ Xs, float* __restrict__ lossT) {
  __shared__ float aw[128];
  __shared__ float red[128];
  int b = blockIdx.x, t = threadIdx.x;
  float acc = 0.f;
  for (int k0 = 0; k0 < B_N; k0 += 128) {
    __syncthreads();
    aw[t] = A[(size_t)b * B_N + k0 + t] / (S[k0 + t] + 1e-5f);
    __syncthreads();
#pragma unroll 16
    for (int kk = 0; kk < 128; kk++) acc += aw[kk] * Xn[(size_t)(k0 + kk) * D_N + t];
  }
  float x2 = Xn[b * D_N + t] + acc;
  float ss = block_reduce_sum<128>(x2 * x2, red);
  float rinv = 1.f / fmaxf(sqrtf(ss), 1e-12f);
  float xs = 3.f * x2 * rinv;
  Xs[b * D_N + t] = xs;
  float dt = block_reduce_sum<128>(xs * Pb[b * D_N + t], red);
  if (t == 0) lossT[b] = fmaxf(18.f - 6.f * dt, 0.f);
}

// K6: big kernel. Dm[b,c] = max(18 - 6*dot(Xs[b], normalize(proxies[c])), 0);
// sumexp[b] += sum_c exp(-Dm[b,c]).  bf16 MFMA 16x16x32.
// grid (256, 4), block 256. Block tile: 128 b x 64 c per chunk.
__global__ __launch_bounds__(256) void k6_big(const float* __restrict__ Xs,
                                              const float* __restrict__ proxies,
                                              float* __restrict__ sumexp) {
  __shared__ __align__(16) unsigned short sX[128 * 136];
  __shared__ __align__(16) unsigned short sP[64 * 136];
  __shared__ float sNorm[64];
  __shared__ float sInv[64];
  const int t = threadIdx.x;
  const int w = t >> 6;       // wave 0..3
  const int lane = t & 63;
  const int lc = lane & 15;   // MFMA row/col within 16
  const int q = lane >> 4;    // quad 0..3
  const int b0 = blockIdx.y * 128;

  // stage Xs tile 128x128 f32 -> bf16 (once per block)
#pragma unroll
  for (int i = 0; i < 16; i++) {
    int f = t + 256 * i;
    int row = f >> 5;
    int col = (f & 31) << 2;
    float4 v = *(const float4*)(Xs + (size_t)(b0 + row) * D_N + col);
    u16x4 pk;
    pk.x = f2bf(v.x); pk.y = f2bf(v.y); pk.z = f2bf(v.z); pk.w = f2bf(v.w);
    *(u16x4*)(sX + row * 136 + col) = pk;
  }
  __syncthreads();

  // A-fragments persist in registers: wave w owns m rows 32w..32w+31 (2 tiles)
  short8 afr[2][4];
#pragma unroll
  for (int mt = 0; mt < 2; mt++)
#pragma unroll
    for (int ks = 0; ks < 4; ks++)
      afr[mt][ks] = *(const short8*)(sX + (32 * w + 16 * mt + lc) * 136 + ks * 32 + q * 8);

  for (int cc = blockIdx.x; cc < NCHUNK; cc += gridDim.x) {
    const int c0 = cc * 64;
    __syncthreads();  // protect sP/sNorm/sInv from previous iteration readers
    // stage 64 proxy rows f32 -> bf16, accumulate row norms via 32-lane shuffle
#pragma unroll
    for (int i = 0; i < 8; i++) {
      int f = t + 256 * i;
      int row = f >> 5;
      int col = (f & 31) << 2;
      int cg = c0 + row;
      float4 v = make_float4(0.f, 0.f, 0.f, 0.f);
      if (cg < C_N) v = *(const float4*)(proxies + (size_t)cg * D_N + col);
      u16x4 pk;
      pk.x = f2bf(v.x); pk.y = f2bf(v.y); pk.z = f2bf(v.z); pk.w = f2bf(v.w);
      *(u16x4*)(sP + row * 136 + col) = pk;
      float ps = v.x * v.x + v.y * v.y + v.z * v.z + v.w * v.w;
      ps += __shfl_xor(ps, 1);
      ps += __shfl_xor(ps, 2);
      ps += __shfl_xor(ps, 4);
      ps += __shfl_xor(ps, 8);
      ps += __shfl_xor(ps, 16);
      if ((lane & 31) == 0) sNorm[2 * w + 8 * i + (lane >> 5)] = ps;
    }
    __syncthreads();
    if (t < 64) sInv[t] = 1.0f / fmaxf(sqrtf(sNorm[t]), 1e-12f);
    __syncthreads();

    f32x4 acc[2][4];
#pragma unroll
    for (int mt = 0; mt < 2; mt++)
#pragma unroll
      for (int nt = 0; nt < 4; nt++) acc[mt][nt] = (f32x4){0.f, 0.f, 0.f, 0.f};

#pragma unroll
    for (int ks = 0; ks < 4; ks++) {
      short8 bfr[4];
#pragma unroll
      for (int nt = 0; nt < 4; nt++)
        bfr[nt] = *(const short8*)(sP + (16 * nt + lc) * 136 + ks * 32 + q * 8);
#pragma unroll
      for (int nt = 0; nt < 4; nt++)
#pragma unroll
        for (int mt = 0; mt < 2; mt++)
          acc[mt][nt] = __builtin_amdgcn_mfma_f32_16x16x32_bf16(afr[mt][ks], bfr[nt],
                                                                acc[mt][nt], 0, 0, 0);
    }

    // epilogue: Dm -> exp -> per-row partial -> reduce over 16-lane col groups -> atomic
#pragma unroll
    for (int mt = 0; mt < 2; mt++) {
      float p0 = 0.f, p1 = 0.f, p2 = 0.f, p3 = 0.f;
#pragma unroll
      for (int nt = 0; nt < 4; nt++) {
        int n = 16 * nt + lc;
        bool ok = (c0 + n) < C_N;
        float inv = sInv[n];
        f32x4 a = acc[mt][nt];
        float e0 = __expf(-fmaxf(18.f - 6.f * a[0] * inv, 0.f));
        float e1 = __expf(-fmaxf(18.f - 6.f * a[1] * inv, 0.f));
        float e2 = __expf(-fmaxf(18.f - 6.f * a[2] * inv, 0.f));
        float e3 = __expf(-fmaxf(18.f - 6.f * a[3] * inv, 0.f));
        p0 += ok ? e0 : 0.f;
        p1 += ok ? e1 : 0.f;
        p2 += ok ? e2 : 0.f;
        p3 += ok ? e3 : 0.f;
      }
#pragma unroll
      for (int off = 1; off <= 8; off <<= 1) {
        p0 += __shfl_xor(p0, off);
        p1 += __shfl_xor(p1, off);
        p2 += __shfl_xor(p2, off);
        p3 += __shfl_xor(p3, off);
      }
      if (lc == 0) {
        int rb = b0 + 32 * w + 16 * mt + 4 * q;
        atomicAdd(&sumexp[rb + 0], p0);
        atomicAdd(&sumexp[rb + 1], p1);
        atomicAdd(&sumexp[rb + 2], p2);
        atomicAdd(&sumexp[rb + 3], p3);
      }
    }
  }
}

// K7: loss = mean_b (lossT[b] + log(sumexp[b]))   1 block x 512
__global__ void k7_final(const float* __restrict__ lossT, const float* __restrict__ sumexp,
                         float* __restrict__ out) {
  __shared__ float red[512];
  int t = threadIdx.x;
  float v = lossT[t] + logf(sumexp[t]);
  float s = block_reduce_sum<512>(v, red);
  if (t == 0) out[0] = s * (1.0f / 512.0f);
}

extern "C" void kernel_launch(void* const* d_in, const int* in_sizes, int n_in,
                              void* d_out, int out_size, void* d_ws, size_t ws_size,
                              hipStream_t stream) {
  const float* X = (const float*)d_in[0];
  // d_in[1] = indices (unused by reference)
  const int* T = (const int*)d_in[2];
  const float* proxies = (const float*)d_in[3];
  float* out = (float*)d_out;

  float* ws = (float*)d_ws;
  float* Xn = ws;                   // 512*128
  float* Pb = Xn + B_N * D_N;       // 512*128
  float* dg = Pb + B_N * D_N;       // 512
  float* S = dg + B_N;              // 512
  float* lossT = S + B_N;           // 512
  float* sumexp = lossT + B_N;      // 512
  float* Xs = sumexp + B_N;         // 512*128
  float* A = Xs + B_N * D_N;        // 512*512

  k1_norm_x<<<B_N, 128, 0, stream>>>(X, Xn);
  k2_pb<<<B_N, 128, 0, stream>>>(proxies, T, Xn, Pb, dg);
  k3_att<<<B_N, 256, 0, stream>>>(Xn, Pb, dg, A, S);
  k4_xs<<<B_N, 128, 0, stream>>>(Xn, Pb, A, S, Xs, lossT);
  hipMemsetAsync(sumexp, 0, B_N * sizeof(float), stream);
  k6_big<<<dim3(256, 4), 256, 0, stream>>>(Xs, proxies, sumexp);
  k7_final<<<1, 512, 0, stream>>>(lossT, sumexp, out);
}

// Round 2
// 167.013 us; speedup vs baseline: 2.2089x; 2.2089x over previous
//
#include <hip/hip_runtime.h>
#include <hip/hip_bf16.h>
#include <math.h>

#define B_N 512
#define C_N 100000
#define CPAD 100032          // padded to multiple of 64
#define D_N 128
#define NCHUNK (CPAD / 64)   // 1563

typedef short short8 __attribute__((ext_vector_type(8)));
typedef float f32x4 __attribute__((ext_vector_type(4)));

__device__ __forceinline__ unsigned short f2bf(float f) {
  unsigned int u = __float_as_uint(f);
  u += 0x7fffu + ((u >> 16) & 1u);
  return (unsigned short)(u >> 16);
}

__device__ __forceinline__ void gl_lds16(const void* g, void* l) {
  __builtin_amdgcn_global_load_lds(
      (const __attribute__((address_space(1))) void*)g,
      (__attribute__((address_space(3))) void*)l, 16, 0, 0);
}

template <int NT>
__device__ __forceinline__ float block_reduce_sum(float v, float* red) {
  int t = threadIdx.x;
  __syncthreads();
  red[t] = v;
  __syncthreads();
#pragma unroll
  for (int s = NT / 2; s > 0; s >>= 1) {
    if (t < s) red[t] += red[t + s];
    __syncthreads();
  }
  return red[0];
}

// K12: Xn = l2norm(X); Pb = l2norm(proxies[T[b]]); diag = Pb[b].Xn[b]
__global__ void k12_norm(const float* __restrict__ X, const float* __restrict__ proxies,
                         const int* __restrict__ T, float* __restrict__ Xn,
                         float* __restrict__ Pb, float* __restrict__ diagv) {
  __shared__ float red[128];
  int b = blockIdx.x, t = threadIdx.x;
  float v = X[b * D_N + t];
  float ss = block_reduce_sum<128>(v * v, red);
  float xn = v / fmaxf(sqrtf(ss), 1e-12f);
  Xn[b * D_N + t] = xn;
  int row = T[b];
  float p = proxies[(size_t)row * D_N + t];
  float ss2 = block_reduce_sum<128>(p * p, red);
  float pn = p / fmaxf(sqrtf(ss2), 1e-12f);
  Pb[b * D_N + t] = pn;
  float d = block_reduce_sum<128>(pn * xn, red);
  if (t == 0) diagv[b] = d;
}

// K3: A[b,k] = relu(0.5*(Pb[b].Xn[k]+diag[k])) + relu(Xn[b].Xn[k]); S[b]=row sum
__global__ __launch_bounds__(256) void k3_att(const float* __restrict__ Xn,
                                              const float* __restrict__ Pb,
                                              const float* __restrict__ diagv,
                                              float* __restrict__ A, float* __restrict__ S) {
  __shared__ float xb[128], pbv[128];
  __shared__ float red[256];
  int b = blockIdx.x, t = threadIdx.x;
  if (t < 128) {
    xb[t] = Xn[b * D_N + t];
    pbv[t] = Pb[b * D_N + t];
  }
  __syncthreads();
  float rs = 0.f;
  for (int k = t; k < B_N; k += 256) {
    const float4* xr = (const float4*)(Xn + (size_t)k * D_N);
    float d1 = 0.f, d2 = 0.f;
#pragma unroll
    for (int i = 0; i < 32; i++) {
      float4 v = xr[i];
      d1 += pbv[4 * i] * v.x + pbv[4 * i + 1] * v.y + pbv[4 * i + 2] * v.z + pbv[4 * i + 3] * v.w;
      d2 += xb[4 * i] * v.x + xb[4 * i + 1] * v.y + xb[4 * i + 2] * v.z + xb[4 * i + 3] * v.w;
    }
    float a = fmaxf(0.5f * (d1 + diagv[k]), 0.f) + fmaxf(d2, 0.f);
    A[(size_t)b * B_N + k] = a;
    rs += a;
  }
  rs = block_reduce_sum<256>(rs, red);
  if (t == 0) S[b] = rs;
}

// K4a: X2[b,:] += sum over k-slice of (A[b,k]/(S[k]+eps)) * Xn[k,:]   grid (512,4)
__global__ void k4a_aw(const float* __restrict__ Xn, const float* __restrict__ A,
                       const float* __restrict__ S, float* __restrict__ X2) {
  __shared__ float aw[128];
  int b = blockIdx.x, t = threadIdx.x;
  int k0 = blockIdx.y * 128;
  aw[t] = A[(size_t)b * B_N + k0 + t] / (S[k0 + t] + 1e-5f);
  __syncthreads();
  float acc = 0.f;
#pragma unroll 16
  for (int kk = 0; kk < 128; kk++) acc += aw[kk] * Xn[(size_t)(k0 + kk) * D_N + t];
  atomicAdd(&X2[b * D_N + t], acc);
}

// K4b: Xsb = bf16(3*l2norm(Xn+X2)); lossT[b] = max(18 - 6*Xs.Pb, 0)
__global__ void k4b_xs(const float* __restrict__ Xn, const float* __restrict__ X2,
                       const float* __restrict__ Pb, unsigned short* __restrict__ Xsb,
                       float* __restrict__ lossT) {
  __shared__ float red[128];
  int b = blockIdx.x, t = threadIdx.x;
  float x2 = Xn[b * D_N + t] + X2[b * D_N + t];
  float ss = block_reduce_sum<128>(x2 * x2, red);
  float xs = 3.f * x2 / fmaxf(sqrtf(ss), 1e-12f);
  Xsb[b * D_N + t] = f2bf(xs);
  float dt = block_reduce_sum<128>(xs * Pb[b * D_N + t], red);
  if (t == 0) lossT[b] = fmaxf(18.f - 6.f * dt, 0.f);
}

// K5: Pnb = bf16(l2norm(proxies)), rows >= C_N zeroed. One wave per row.
__global__ __launch_bounds__(256) void k5_pn(const float* __restrict__ proxies,
                                             unsigned short* __restrict__ Pnb) {
  int t = threadIdx.x;
  int lane = t & 63;
  int row = blockIdx.x * 4 + (t >> 6);
  float2 v = make_float2(0.f, 0.f);
  if (row < C_N) v = *(const float2*)(proxies + (size_t)row * D_N + 2 * lane);
  float ss = v.x * v.x + v.y * v.y;
#pragma unroll
  for (int off = 1; off < 64; off <<= 1) ss += __shfl_xor(ss, off);
  float inv = 1.f / fmaxf(sqrtf(ss), 1e-12f);
  unsigned short a = f2bf(v.x * inv), b = f2bf(v.y * inv);
  unsigned int pk = (unsigned int)a | ((unsigned int)b << 16);
  *(unsigned int*)(Pnb + (size_t)row * D_N + 2 * lane) = pk;
}

// K6: Dm[b,c] = max(18 - 6*dot(Xs[b], Pn[c]), 0); sumexp[b] += sum_c exp(-Dm)
// grid (256,4), block 256. Tile 128 b-rows x 64 c-cols. Double-buffered DMA staging.
__global__ __launch_bounds__(256, 4) void k6_big(const unsigned short* __restrict__ Pnb,
                                                 const unsigned short* __restrict__ Xsb,
                                                 float* __restrict__ sumexpP) {
  __shared__ __align__(16) unsigned short sP[2][64 * 128];  // 2 x 16 KB, XOR-swizzled granules
  const int t = threadIdx.x;
  const int w = t >> 6;
  const int lane = t & 63;
  const int lc = lane & 15;
  const int q = lane >> 4;
  const int b0 = blockIdx.y * 128;

  // A-fragments once from global bf16 Xsb: A[m=lc][k=ks*32+q*8+j]
  short8 afr[2][4];
#pragma unroll
  for (int mt = 0; mt < 2; mt++)
#pragma unroll
    for (int ks = 0; ks < 4; ks++)
      afr[mt][ks] = *(const short8*)(Xsb + (size_t)(b0 + 32 * w + 16 * mt + lc) * D_N +
                                     ks * 32 + q * 8);

  // per-lane exp partial sums, accumulated across all chunks
  float pe[2][4];
#pragma unroll
  for (int mt = 0; mt < 2; mt++)
#pragma unroll
    for (int r = 0; r < 4; r++) pe[mt][r] = 0.f;

  // staging: wave w stages rows 16w..16w+15 (4 instr x 1024 B). Dest granule
  // (R,P) holds global granule g = P ^ (R&15) of row c0+R (bank-conflict swizzle).
  const int rR = 16 * w + (lane >> 4);           // per-instr j: row = rR + 4*j
  const int gsrc0 = (lane & 15);                 // P
#define STAGE(c0_, buf_)                                                              \
  {                                                                                   \
    _Pragma("unroll") for (int j = 0; j < 4; j++) {                                   \
      int R = rR + 4 * j;                                                             \
      int g = gsrc0 ^ ((R)&15);                                                       \
      gl_lds16(Pnb + (((size_t)(c0_) + R) << 7) + (g << 3),                           \
               &sP[buf_][w * 2048 + j * 512]);                                        \
    }                                                                                 \
  }

  int cc = blockIdx.x;
  STAGE(cc * 64, 0);
  int buf = 0;
  while (true) {
    __syncthreads();  // drains this buffer's DMA (vmcnt0) + protects buffers
    int nc = cc + gridDim.x;
    if (nc < NCHUNK) STAGE(nc * 64, buf ^ 1);

    const int c0 = cc * 64;
    f32x4 acc[2][4];
#pragma unroll
    for (int mt = 0; mt < 2; mt++)
#pragma unroll
      for (int nt = 0; nt < 4; nt++) acc[mt][nt] = (f32x4){0.f, 0.f, 0.f, 0.f};

#pragma unroll
    for (int ks = 0; ks < 4; ks++) {
      short8 bfr[4];
#pragma unroll
      for (int nt = 0; nt < 4; nt++) {
        int R = 16 * nt + lc;
        int g = (ks * 4 + q) ^ lc;  // R&15 == lc
        bfr[nt] = *(const short8*)(&sP[buf][R * 128 + (g << 3)]);
      }
#pragma unroll
      for (int nt = 0; nt < 4; nt++)
#pragma unroll
        for (int mt = 0; mt < 2; mt++)
          acc[mt][nt] = __builtin_amdgcn_mfma_f32_16x16x32_bf16(afr[mt][ks], bfr[nt],
                                                                acc[mt][nt], 0, 0, 0);
    }

    // epilogue: accumulate exp(-Dm) into registers (no atomics in loop)
#pragma unroll
    for (int mt = 0; mt < 2; mt++) {
#pragma unroll
      for (int nt = 0; nt < 4; nt++) {
        bool ok = (c0 + 16 * nt + lc) < C_N;
        f32x4 a = acc[mt][nt];
#pragma unroll
        for (int r = 0; r < 4; r++) {
          float e = __expf(fminf(6.f * a[r] - 18.f, 0.f));
          pe[mt][r] += ok ? e : 0.f;
        }
      }
    }
    if (nc >= NCHUNK) break;
    cc = nc;
    buf ^= 1;
  }

  // final: reduce over the 16 column-lanes, one padded atomic per row
#pragma unroll
  for (int mt = 0; mt < 2; mt++) {
#pragma unroll
    for (int r = 0; r < 4; r++) {
      float p = pe[mt][r];
      p += __shfl_xor(p, 1);
      p += __shfl_xor(p, 2);
      p += __shfl_xor(p, 4);
      p += __shfl_xor(p, 8);
      if (lc == 0) {
        int rb = b0 + 32 * w + 16 * mt + 4 * q + r;
        atomicAdd(&sumexpP[rb * 16], p);
      }
    }
  }
}

// K7: loss = mean_b (lossT[b] + log(sumexp[b]))
__global__ void k7_final(const float* __restrict__ lossT, const float* __restrict__ sumexpP,
                         float* __restrict__ out) {
  __shared__ float red[512];
  int t = threadIdx.x;
  float v = lossT[t] + logf(sumexpP[t * 16]);
  float s = block_reduce_sum<512>(v, red);
  if (t == 0) out[0] = s * (1.0f / 512.0f);
}

extern "C" void kernel_launch(void* const* d_in, const int* in_sizes, int n_in,
                              void* d_out, int out_size, void* d_ws, size_t ws_size,
                              hipStream_t stream) {
  const float* X = (const float*)d_in[0];
  const int* T = (const int*)d_in[2];
  const float* proxies = (const float*)d_in[3];
  float* out = (float*)d_out;

  char* ws = (char*)d_ws;
  unsigned short* Pnb = (unsigned short*)ws;               // CPAD*128 bf16 = 25.6 MB
  float* Xn = (float*)(ws + (size_t)CPAD * D_N * 2);       // 512*128
  float* Pb = Xn + B_N * D_N;                              // 512*128
  float* X2 = Pb + B_N * D_N;                              // 512*128
  float* dg = X2 + B_N * D_N;                              // 512
  float* S = dg + B_N;                                     // 512
  float* lossT = S + B_N;                                  // 512
  float* sumexpP = lossT + B_N;                            // 512*16 (line-padded)
  unsigned short* Xsb = (unsigned short*)(sumexpP + B_N * 16);  // 512*128 bf16
  float* A = (float*)(Xsb + B_N * D_N);                    // 512*512

  hipMemsetAsync(X2, 0, B_N * D_N * sizeof(float), stream);
  hipMemsetAsync(sumexpP, 0, B_N * 16 * sizeof(float), stream);
  k5_pn<<<CPAD / 4, 256, 0, stream>>>(proxies, Pnb);
  k12_norm<<<B_N, 128, 0, stream>>>(X, proxies, T, Xn, Pb, dg);
  k3_att<<<B_N, 256, 0, stream>>>(Xn, Pb, dg, A, S);
  k4a_aw<<<dim3(B_N, 4), 128, 0, stream>>>(Xn, A, S, X2);
  k4b_xs<<<B_N, 128, 0, stream>>>(Xn, X2, Pb, Xsb, lossT);
  k6_big<<<dim3(256, 4), 256, 0, stream>>>(Pnb, Xsb, sumexpP);
  k7_final<<<1, 512, 0, stream>>>(lossT, sumexpP, out);
}